// Round 3
// baseline (373.102 us; speedup 1.0000x reference)
//
#include <hip/hip_runtime.h>

#define BDIM   256
#define BPB    4      // boards per block (4*729 floats = 11664 B, 16B-aligned groups)
#define KK     9
#define CELLS  81
#define BOARD  729
#define CHUNK  (BPB * BOARD)   // 2916 floats = 729 float4
#define NV4    3               // float4 iterations per thread: ceil(729/256)

typedef float v4f __attribute__((ext_vector_type(4)));   // native vector: OK for nontemporal builtins

__global__ __launch_bounds__(BDIM) void sudoku_iter_kernel(
    const float* __restrict__ sudoku,
    const float* __restrict__ rmask,
    const float* __restrict__ rindex,
    const float* __restrict__ conv_w,
    const float* __restrict__ conv_b,
    float* __restrict__ out,
    int Btot)
{
    __shared__ float lds_s[CHUNK];           // 11664 B
    __shared__ v4f   lmeta[BPB];             // general path only: {m, cms, ri, bitcast((f<<7)|cell)}

    const int tid   = threadIdx.x;
    const int lane  = tid & 63;
    const int wave  = tid >> 6;
    const int block = blockIdx.x;
    const size_t base = (size_t)block * CHUNK;

    // ---- issue ALL independent global loads up front ----
    const v4f* gsrc = (const v4f*)(sudoku + base);
    const v4f* grm  = (const v4f*)(rmask  + base);
    v4f s4[NV4], r4[NV4];
    bool act[NV4];
    #pragma unroll
    for (int i = 0; i < NV4; ++i) {
        int g = tid + i * BDIM;
        act[i] = (g < CHUNK / 4);
        if (act[i]) s4[i] = __builtin_nontemporal_load(&gsrc[g]);
    }
    #pragma unroll
    for (int i = 0; i < NV4; ++i) {
        int g = tid + i * BDIM;
        // REGULAR load (not NT): keeps rmask lines L2-resident for the sparse
        // fixup re-read after barrier2.
        if (act[i]) r4[i] = grm[g];
    }
    float ri0 = 0.f;
    if (lane == 0) ri0 = rindex[block * BPB + wave];       // prefetched early
    const float wlane = conv_w[lane < KK ? lane : KK - 1]; // per-lane weight for n-argmax

    float wreg[KK];
    #pragma unroll
    for (int n = 0; n < KK; ++n) wreg[n] = conv_w[n];
    const float bias = conv_b[0];
    const float cmp  = fminf(fmaxf(bias, 0.f), 1.f);   // cell_mask away from chosen cell
    // fast path: away-from-cell cell_mask is exactly 0 -> orm==0 everywhere
    // except the chosen cell's 9 entries (patched sparsely after barrier2)
    const bool fast = (cmp == 0.f);

    // ---- stage sudoku registers -> LDS ----
    v4f* lds4 = (v4f*)lds_s;
    #pragma unroll
    for (int i = 0; i < NV4; ++i) {
        int g = tid + i * BDIM;
        if (act[i]) lds4[g] = s4[i];
    }
    __syncthreads();   // barrier1

    v4f* gout_s = (v4f*)(out + base);
    v4f* gout_r = (v4f*)(out + (size_t)Btot * BOARD + base);

    if (fast) {
        // ---- bulk copy-through epilogue: does NOT depend on selection, so the
        // store stream issues now and retires while selection runs ----
        #pragma unroll
        for (int i = 0; i < NV4; ++i) {
            int g = tid + i * BDIM;
            if (act[i]) {
                v4f rv = r4[i];
                rv.x = fmaxf(rv.x, 0.f); rv.y = fmaxf(rv.y, 0.f);
                rv.z = fmaxf(rv.z, 0.f); rv.w = fmaxf(rv.w, 0.f);
                __builtin_nontemporal_store(s4[i], &gout_s[g]);
                __builtin_nontemporal_store(rv,    &gout_r[g]);
            }
        }
    }

    // ---- per-board selection: wave w handles board w ----
    const float* bs = lds_s + wave * BOARD;
    int   i0;                      // chosen cell (all lanes)
    float nv; int nn; float nw;    // number-argmax value/index/weight (lanes 0..15 valid)
    {
        const int  cellA  = lane;
        const int  cellB2 = lane + 64;
        const bool okB    = (cellB2 < CELLS);
        const int  cellB  = okB ? cellB2 : (CELLS - 1);
        float cntA = bias, cntB = bias;
        #pragma unroll
        for (int n = 0; n < KK; ++n) {
            cntA += bs[n * CELLS + cellA] * wreg[n];
            cntB += bs[n * CELLS + cellB] * wreg[n];
        }
        float nicA = fmaxf(cntA - 1.f, 0.f);
        float v0   = fminf(fmaxf(1.f - nicA, 0.f), 1.f) * (-(float)KK) - nicA;
        i0 = cellA;
        float nicB = fmaxf(cntB - 1.f, 0.f);
        float vB   = fminf(fmaxf(1.f - nicB, 0.f), 1.f) * (-(float)KK) - nicB;
        if (!okB) vB = -1e30f;
        if (vB > v0) { v0 = vB; i0 = cellB; }   // strict: tie keeps smaller index

        // butterfly argmax-first over 64 lanes (max value; tie -> smaller cell)
        #pragma unroll
        for (int off = 32; off > 0; off >>= 1) {
            float ov = __shfl_xor(v0, off, 64);
            int   oi = __shfl_xor(i0, off, 64);
            if (ov > v0 || (ov == v0 && oi < i0)) { v0 = ov; i0 = oi; }
        }
        // all lanes now agree on chosen cell i0

        // wave-parallel first-argmax over the 9 numbers (lanes 0..8), carrying
        // the matching conv weight so no dynamic wreg[] indexing is needed
        nv = (lane < KK) ? bs[lane * CELLS + i0] : -1e30f;
        nn = lane;
        nw = wlane;
        #pragma unroll
        for (int off = 8; off > 0; off >>= 1) {
            float ov = __shfl_xor(nv, off, 16);
            int   oi = __shfl_xor(nn, off, 16);
            float ow = __shfl_xor(nw, off, 16);
            if (ov > nv || (ov == nv && oi < nn)) { nv = ov; nn = oi; nw = ow; }
        }
    }
    const float riv = __shfl(ri0, 0, 64);                  // broadcast recursion_index
    const float cms = fminf(fmaxf(nv * nw + bias, 0.f), 1.f);

    if (!fast && lane == 0) {
        int pk = ((wave * BOARD + nn * CELLS + i0) << 7) | i0;
        v4f md;
        md.x = nv; md.y = cms; md.z = ri0; md.w = __int_as_float(pk);
        lmeta[wave] = md;
    }
    __syncthreads();   // barrier2: drains all waves' bulk stores (orders fixup after them)

    if (fast) {
        // ---- sparse fixup: lanes 0..8 of wave w patch board w's chosen cell ----
        if (lane < KK) {
            const int e  = wave * BOARD + lane * CELLS + i0;   // chunk element index
            float s  = lds_s[e];
            float rm = rmask[base + e];                        // L2-hot (regular-loaded above)
            float ov  = (lane == nn) ? nv : 0.f;               // one_variant
            float orm = s * cms * (1.f - ov);                  // one_recursion_mask
            float rmo = fmaxf(rm, riv * orm);
            rmo = fmaxf(rmo, (riv - 1.f) * ov);
            out[base + e]                         = s * (1.f - orm);
            out[(size_t)Btot * BOARD + base + e]  = rmo;
        }
        if (lane == KK) {
            out[(size_t)Btot * BOARD * 2 + (size_t)block * BPB + wave] = riv + 1.f;
        }
        return;
    }

    // ---- general path (cmp != 0): full per-element epilogue from registers ----
    if (tid < BPB) {
        out[(size_t)Btot * BOARD * 2 + (size_t)block * BPB + tid] = lmeta[tid].z + 1.f;
    }
    const int c0 = (4 * tid) % 81;
    const int iadd[NV4] = {0, 52, 23};     // (1024*i) % 81

    #pragma unroll
    for (int i = 0; i < NV4; ++i) {
        int g = tid + i * BDIM;
        if (act[i]) {
            int f0 = 4 * g;                                   // 0..2912
            float so[4], ro[4];
            const float* sp = (const float*)&s4[i];
            const float* rp = (const float*)&r4[i];
            #pragma unroll
            for (int j = 0; j < 4; ++j) {
                int f = f0 + j;
                int blj = (f >= 1458) ? (f >= 2187 ? 3 : 2) : (f >= 729 ? 1 : 0);
                int cell = c0 + iadd[i] + j;                  // f % 81, folded
                if (cell >= 81) cell -= 81;
                v4f md = lmeta[blj];                          // single ds_read_b128
                float m   = md.x;
                float cmsj= md.y;
                float rivj= md.z;
                int   pk  = __float_as_int(md.w);
                float s  = sp[j];
                float rm = rp[j];
                float ov  = (f == (pk >> 7)) ? m : 0.f;                   // one_variant
                float cm  = (cell == (pk & 127)) ? cmsj : cmp;
                float orm = s * cm * (1.f - ov);                          // one_recursion_mask
                float rmo = fmaxf(rm, rivj * orm);
                rmo = fmaxf(rmo, (rivj - 1.f) * ov);
                so[j] = s * (1.f - orm);
                ro[j] = rmo;
            }
            v4f sv; sv.x = so[0]; sv.y = so[1]; sv.z = so[2]; sv.w = so[3];
            v4f rv; rv.x = ro[0]; rv.y = ro[1]; rv.z = ro[2]; rv.w = ro[3];
            __builtin_nontemporal_store(sv, &gout_s[g]);
            __builtin_nontemporal_store(rv, &gout_r[g]);
        }
    }
}

extern "C" void kernel_launch(void* const* d_in, const int* in_sizes, int n_in,
                              void* d_out, int out_size, void* d_ws, size_t ws_size,
                              hipStream_t stream) {
    const float* sudoku = (const float*)d_in[0];
    const float* rmask  = (const float*)d_in[1];
    const float* rindex = (const float*)d_in[2];
    const float* conv_w = (const float*)d_in[3];
    const float* conv_b = (const float*)d_in[4];
    float* out = (float*)d_out;

    const int Btot = in_sizes[2];            // 32768 boards
    const int nblocks = Btot / BPB;          // 8192

    sudoku_iter_kernel<<<nblocks, BDIM, 0, stream>>>(
        sudoku, rmask, rindex, conv_w, conv_b, out, Btot);
}

// Round 4
// 334.578 us; speedup vs baseline: 1.1151x; 1.1151x over previous
//
#include <hip/hip_runtime.h>

#define BDIM   256
#define BPB    4      // boards per block (4*729 floats = 11664 B, 16B-aligned groups)
#define KK     9
#define CELLS  81
#define BOARD  729
#define CHUNK  (BPB * BOARD)   // 2916 floats = 729 float4
#define NV4    3               // float4 iterations per thread: ceil(729/256)

typedef float v4f __attribute__((ext_vector_type(4)));   // native vector: OK for nontemporal builtins

__global__ __launch_bounds__(BDIM) void sudoku_iter_kernel(
    const float* __restrict__ sudoku,
    const float* __restrict__ rmask,
    const float* __restrict__ rindex,
    const float* __restrict__ conv_w,
    const float* __restrict__ conv_b,
    float* __restrict__ out,
    int Btot)
{
    __shared__ float lds_s[CHUNK];           // 11664 B
    __shared__ v4f   lmeta[BPB];             // per board: {m, cms, ri, bitcast((fchosen<<7)|cell)}

    const int tid   = threadIdx.x;
    const int lane  = tid & 63;
    const int wave  = tid >> 6;
    const int block = blockIdx.x;
    const size_t base = (size_t)block * CHUNK;

    // ---- issue ALL independent global loads up front: sudoku (LDS stage waits
    // only on these), rmask (stays in flight across both barriers), rindex
    // (consumed only at END of selection -> latency fully hidden), weights ----
    // R4 change: REGULAR (cacheable) input loads — inputs are freshly written
    // by the harness reset and largely L3-resident; the nt evict-first hint
    // was discarding that residency (R3 FETCH evidence). Stores stay NT.
    const v4f* gsrc = (const v4f*)(sudoku + base);
    const v4f* grm  = (const v4f*)(rmask  + base);
    v4f s4[NV4], r4[NV4];
    bool act[NV4];
    #pragma unroll
    for (int i = 0; i < NV4; ++i) {
        int g = tid + i * BDIM;
        act[i] = (g < CHUNK / 4);
        if (act[i]) s4[i] = gsrc[g];
    }
    #pragma unroll
    for (int i = 0; i < NV4; ++i) {
        int g = tid + i * BDIM;
        if (act[i]) r4[i] = grm[g];
    }
    float ri0 = 0.f;
    if (lane == 0) ri0 = rindex[block * BPB + wave];       // prefetched early
    const float wlane = conv_w[lane < KK ? lane : KK - 1]; // per-lane weight for n-argmax

    float wreg[KK];
    #pragma unroll
    for (int n = 0; n < KK; ++n) wreg[n] = conv_w[n];
    const float bias = conv_b[0];
    const float cmp  = fminf(fmaxf(bias, 0.f), 1.f);   // cell_mask away from chosen cell

    // ---- stage sudoku registers -> LDS (waits only on sudoku vmcnt slice) ----
    v4f* lds4 = (v4f*)lds_s;
    #pragma unroll
    for (int i = 0; i < NV4; ++i) {
        int g = tid + i * BDIM;
        if (act[i]) lds4[g] = s4[i];
    }
    __syncthreads();

    // ---- per-board selection: wave w handles board w ----
    {
        const float* bs = lds_s + wave * BOARD;

        // both candidate cells unconditionally (uniform control flow lets the
        // compiler fuse each n-pair into ds_read2_b32 offset1:64)
        const int  cellA  = lane;
        const int  cellB2 = lane + 64;
        const bool okB    = (cellB2 < CELLS);
        const int  cellB  = okB ? cellB2 : (CELLS - 1);
        float cntA = bias, cntB = bias;
        #pragma unroll
        for (int n = 0; n < KK; ++n) {
            cntA += bs[n * CELLS + cellA] * wreg[n];
            cntB += bs[n * CELLS + cellB] * wreg[n];
        }
        float nicA = fmaxf(cntA - 1.f, 0.f);
        float v0   = fminf(fmaxf(1.f - nicA, 0.f), 1.f) * (-(float)KK) - nicA;
        int   i0   = cellA;
        float nicB = fmaxf(cntB - 1.f, 0.f);
        float vB   = fminf(fmaxf(1.f - nicB, 0.f), 1.f) * (-(float)KK) - nicB;
        if (!okB) vB = -1e30f;
        if (vB > v0) { v0 = vB; i0 = cellB; }   // strict: tie keeps smaller index

        // butterfly argmax-first over 64 lanes (max value; tie -> smaller cell)
        #pragma unroll
        for (int off = 32; off > 0; off >>= 1) {
            float ov = __shfl_xor(v0, off, 64);
            int   oi = __shfl_xor(i0, off, 64);
            if (ov > v0 || (ov == v0 && oi < i0)) { v0 = ov; i0 = oi; }
        }
        // all lanes now agree on chosen cell i0

        // wave-parallel first-argmax over the 9 numbers (lanes 0..8), carrying
        // the matching conv weight so no dynamic wreg[] indexing is needed
        float nv = (lane < KK) ? bs[lane * CELLS + i0] : -1e30f;
        int   nn = lane;
        float nw = wlane;
        #pragma unroll
        for (int off = 8; off > 0; off >>= 1) {
            float ov = __shfl_xor(nv, off, 16);
            int   oi = __shfl_xor(nn, off, 16);
            float ow = __shfl_xor(nw, off, 16);
            if (ov > nv || (ov == nv && oi < nn)) { nv = ov; nn = oi; nw = ow; }
        }
        if (lane == 0) {
            // pack chunk-element index of chosen (number,cell) + chosen cell
            int pk = ((wave * BOARD + nn * CELLS + i0) << 7) | i0;
            v4f md;
            md.x = nv;                                             // m
            md.y = fminf(fmaxf(nv * nw + bias, 0.f), 1.f);         // cms
            md.z = ri0;                                            // recursion_index
            md.w = __int_as_float(pk);
            lmeta[wave] = md;
        }
    }
    __syncthreads();

    // recursion_index + 1 output (one float per board) — issue before main loop
    if (tid < BPB) {
        out[(size_t)Btot * BOARD * 2 + (size_t)block * BPB + tid] = lmeta[tid].z + 1.f;
    }

    // ---- elementwise epilogue from REGISTERS (one ds_read_b128 of meta/elem) ----
    v4f* gout_s = (v4f*)(out + base);
    v4f* gout_r = (v4f*)(out + (size_t)Btot * BOARD + base);

    // cell index: f = 4*tid + 1024*i + j; cell = f % 81 (since 729 = 9*81).
    // c0 = (4*tid)%81 once; per (i,j) add {0,52,23}[i]+j then one cond-subtract.
    const int c0 = (4 * tid) % 81;
    const int iadd[NV4] = {0, 52, 23};     // (1024*i) % 81

    #pragma unroll
    for (int i = 0; i < NV4; ++i) {
        int g = tid + i * BDIM;
        if (act[i]) {
            int f0 = 4 * g;                                   // 0..2912
            float so[4], ro[4];
            const float* sp = (const float*)&s4[i];
            const float* rp = (const float*)&r4[i];
            #pragma unroll
            for (int j = 0; j < 4; ++j) {
                int f = f0 + j;
                int blj = (f >= 1458) ? (f >= 2187 ? 3 : 2) : (f >= 729 ? 1 : 0);
                int cell = c0 + iadd[i] + j;                  // f % 81, folded
                if (cell >= 81) cell -= 81;
                v4f md = lmeta[blj];                          // single ds_read_b128
                float m   = md.x;
                float cms = md.y;
                float riv = md.z;
                int   pk  = __float_as_int(md.w);
                float s  = sp[j];
                float rm = rp[j];
                float ov  = (f == (pk >> 7)) ? m : 0.f;                   // one_variant
                float cm  = (cell == (pk & 127)) ? cms : cmp;
                float orm = s * cm * (1.f - ov);                          // one_recursion_mask
                float rmo = fmaxf(rm, riv * orm);
                rmo = fmaxf(rmo, (riv - 1.f) * ov);
                so[j] = s * (1.f - orm);
                ro[j] = rmo;
            }
            v4f sv; sv.x = so[0]; sv.y = so[1]; sv.z = so[2]; sv.w = so[3];
            v4f rv; rv.x = ro[0]; rv.y = ro[1]; rv.z = ro[2]; rv.w = ro[3];
            __builtin_nontemporal_store(sv, &gout_s[g]);
            __builtin_nontemporal_store(rv, &gout_r[g]);
        }
    }
}

extern "C" void kernel_launch(void* const* d_in, const int* in_sizes, int n_in,
                              void* d_out, int out_size, void* d_ws, size_t ws_size,
                              hipStream_t stream) {
    const float* sudoku = (const float*)d_in[0];
    const float* rmask  = (const float*)d_in[1];
    const float* rindex = (const float*)d_in[2];
    const float* conv_w = (const float*)d_in[3];
    const float* conv_b = (const float*)d_in[4];
    float* out = (float*)d_out;

    const int Btot = in_sizes[2];            // 32768 boards
    const int nblocks = Btot / BPB;          // 8192

    sudoku_iter_kernel<<<nblocks, BDIM, 0, stream>>>(
        sudoku, rmask, rindex, conv_w, conv_b, out, Btot);
}

// Round 5
// 313.850 us; speedup vs baseline: 1.1888x; 1.0660x over previous
//
#include <hip/hip_runtime.h>

#define BDIM   256
#define BPB    4      // boards per block (4*729 floats = 11664 B, 16B-aligned groups)
#define KK     9
#define CELLS  81
#define BOARD  729
#define CHUNK  (BPB * BOARD)   // 2916 floats = 729 float4
#define NV4    3               // float4 iterations per thread: ceil(729/256)

typedef float v4f __attribute__((ext_vector_type(4)));   // native vector: OK for nontemporal builtins

__global__ __launch_bounds__(BDIM) void sudoku_iter_kernel(
    const float* __restrict__ sudoku,
    const float* __restrict__ rmask,
    const float* __restrict__ rindex,
    const float* __restrict__ conv_w,
    const float* __restrict__ conv_b,
    float* __restrict__ out,
    int Btot)
{
    __shared__ float lds_s[CHUNK];           // 11664 B
    __shared__ v4f   lmeta[BPB];             // per board: {m, cms, ri, bitcast((fchosen<<7)|cell)}

    const int tid   = threadIdx.x;
    const int lane  = tid & 63;
    const int wave  = tid >> 6;
    const int block = blockIdx.x;
    const size_t base = (size_t)block * CHUNK;

    // ---- issue ALL independent global loads up front: sudoku (LDS stage waits
    // only on these), rmask (stays in flight across both barriers), rindex
    // (consumed only at END of selection -> latency fully hidden), weights ----
    // Cache policy (measured, R1/R2/R4): NT loads + NT stores is the best
    // quadrant. NT loads bypass L1/L2 allocation for touch-once data (L3
    // serves ~half the input stream either way — R3/R4 FETCH evidence);
    // regular loads cost +20 µs (R4), regular stores +3 µs (R2).
    const v4f* gsrc = (const v4f*)(sudoku + base);
    const v4f* grm  = (const v4f*)(rmask  + base);
    v4f s4[NV4], r4[NV4];
    bool act[NV4];
    #pragma unroll
    for (int i = 0; i < NV4; ++i) {
        int g = tid + i * BDIM;
        act[i] = (g < CHUNK / 4);
        if (act[i]) s4[i] = __builtin_nontemporal_load(&gsrc[g]);
    }
    #pragma unroll
    for (int i = 0; i < NV4; ++i) {
        int g = tid + i * BDIM;
        if (act[i]) r4[i] = __builtin_nontemporal_load(&grm[g]);
    }
    float ri0 = 0.f;
    if (lane == 0) ri0 = rindex[block * BPB + wave];       // prefetched early
    const float wlane = conv_w[lane < KK ? lane : KK - 1]; // per-lane weight for n-argmax

    float wreg[KK];
    #pragma unroll
    for (int n = 0; n < KK; ++n) wreg[n] = conv_w[n];
    const float bias = conv_b[0];
    const float cmp  = fminf(fmaxf(bias, 0.f), 1.f);   // cell_mask away from chosen cell

    // ---- stage sudoku registers -> LDS (waits only on sudoku vmcnt slice) ----
    v4f* lds4 = (v4f*)lds_s;
    #pragma unroll
    for (int i = 0; i < NV4; ++i) {
        int g = tid + i * BDIM;
        if (act[i]) lds4[g] = s4[i];
    }
    __syncthreads();

    // ---- per-board selection: wave w handles board w ----
    {
        const float* bs = lds_s + wave * BOARD;

        // both candidate cells unconditionally (uniform control flow lets the
        // compiler fuse each n-pair into ds_read2_b32 offset1:64)
        const int  cellA  = lane;
        const int  cellB2 = lane + 64;
        const bool okB    = (cellB2 < CELLS);
        const int  cellB  = okB ? cellB2 : (CELLS - 1);
        float cntA = bias, cntB = bias;
        #pragma unroll
        for (int n = 0; n < KK; ++n) {
            cntA += bs[n * CELLS + cellA] * wreg[n];
            cntB += bs[n * CELLS + cellB] * wreg[n];
        }
        float nicA = fmaxf(cntA - 1.f, 0.f);
        float v0   = fminf(fmaxf(1.f - nicA, 0.f), 1.f) * (-(float)KK) - nicA;
        int   i0   = cellA;
        float nicB = fmaxf(cntB - 1.f, 0.f);
        float vB   = fminf(fmaxf(1.f - nicB, 0.f), 1.f) * (-(float)KK) - nicB;
        if (!okB) vB = -1e30f;
        if (vB > v0) { v0 = vB; i0 = cellB; }   // strict: tie keeps smaller index

        // butterfly argmax-first over 64 lanes (max value; tie -> smaller cell)
        #pragma unroll
        for (int off = 32; off > 0; off >>= 1) {
            float ov = __shfl_xor(v0, off, 64);
            int   oi = __shfl_xor(i0, off, 64);
            if (ov > v0 || (ov == v0 && oi < i0)) { v0 = ov; i0 = oi; }
        }
        // all lanes now agree on chosen cell i0

        // wave-parallel first-argmax over the 9 numbers (lanes 0..8), carrying
        // the matching conv weight so no dynamic wreg[] indexing is needed
        float nv = (lane < KK) ? bs[lane * CELLS + i0] : -1e30f;
        int   nn = lane;
        float nw = wlane;
        #pragma unroll
        for (int off = 8; off > 0; off >>= 1) {
            float ov = __shfl_xor(nv, off, 16);
            int   oi = __shfl_xor(nn, off, 16);
            float ow = __shfl_xor(nw, off, 16);
            if (ov > nv || (ov == nv && oi < nn)) { nv = ov; nn = oi; nw = ow; }
        }
        if (lane == 0) {
            // pack chunk-element index of chosen (number,cell) + chosen cell
            int pk = ((wave * BOARD + nn * CELLS + i0) << 7) | i0;
            v4f md;
            md.x = nv;                                             // m
            md.y = fminf(fmaxf(nv * nw + bias, 0.f), 1.f);         // cms
            md.z = ri0;                                            // recursion_index
            md.w = __int_as_float(pk);
            lmeta[wave] = md;
        }
    }
    __syncthreads();

    // recursion_index + 1 output (one float per board) — issue before main loop
    if (tid < BPB) {
        out[(size_t)Btot * BOARD * 2 + (size_t)block * BPB + tid] = lmeta[tid].z + 1.f;
    }

    // ---- elementwise epilogue from REGISTERS (one ds_read_b128 of meta/elem) ----
    v4f* gout_s = (v4f*)(out + base);
    v4f* gout_r = (v4f*)(out + (size_t)Btot * BOARD + base);

    // cell index: f = 4*tid + 1024*i + j; cell = f % 81 (since 729 = 9*81).
    // c0 = (4*tid)%81 once; per (i,j) add {0,52,23}[i]+j then one cond-subtract.
    const int c0 = (4 * tid) % 81;
    const int iadd[NV4] = {0, 52, 23};     // (1024*i) % 81

    #pragma unroll
    for (int i = 0; i < NV4; ++i) {
        int g = tid + i * BDIM;
        if (act[i]) {
            int f0 = 4 * g;                                   // 0..2912
            float so[4], ro[4];
            const float* sp = (const float*)&s4[i];
            const float* rp = (const float*)&r4[i];
            #pragma unroll
            for (int j = 0; j < 4; ++j) {
                int f = f0 + j;
                int blj = (f >= 1458) ? (f >= 2187 ? 3 : 2) : (f >= 729 ? 1 : 0);
                int cell = c0 + iadd[i] + j;                  // f % 81, folded
                if (cell >= 81) cell -= 81;
                v4f md = lmeta[blj];                          // single ds_read_b128
                float m   = md.x;
                float cms = md.y;
                float riv = md.z;
                int   pk  = __float_as_int(md.w);
                float s  = sp[j];
                float rm = rp[j];
                float ov  = (f == (pk >> 7)) ? m : 0.f;                   // one_variant
                float cm  = (cell == (pk & 127)) ? cms : cmp;
                float orm = s * cm * (1.f - ov);                          // one_recursion_mask
                float rmo = fmaxf(rm, riv * orm);
                rmo = fmaxf(rmo, (riv - 1.f) * ov);
                so[j] = s * (1.f - orm);
                ro[j] = rmo;
            }
            v4f sv; sv.x = so[0]; sv.y = so[1]; sv.z = so[2]; sv.w = so[3];
            v4f rv; rv.x = ro[0]; rv.y = ro[1]; rv.z = ro[2]; rv.w = ro[3];
            __builtin_nontemporal_store(sv, &gout_s[g]);
            __builtin_nontemporal_store(rv, &gout_r[g]);
        }
    }
}

extern "C" void kernel_launch(void* const* d_in, const int* in_sizes, int n_in,
                              void* d_out, int out_size, void* d_ws, size_t ws_size,
                              hipStream_t stream) {
    const float* sudoku = (const float*)d_in[0];
    const float* rmask  = (const float*)d_in[1];
    const float* rindex = (const float*)d_in[2];
    const float* conv_w = (const float*)d_in[3];
    const float* conv_b = (const float*)d_in[4];
    float* out = (float*)d_out;

    const int Btot = in_sizes[2];            // 32768 boards
    const int nblocks = Btot / BPB;          // 8192

    sudoku_iter_kernel<<<nblocks, BDIM, 0, stream>>>(
        sudoku, rmask, rindex, conv_w, conv_b, out, Btot);
}